// Round 1
// 1510.135 us; speedup vs baseline: 1.3650x; 1.3650x over previous
//
#include <hip/hip_runtime.h>

#define NNODES 50000
#define NEDGES 1600000
#define IN_DIM 512
#define K1 1024
#define H1 2048
#define H2 2048
#define OUT_DIM 512
#define MTILES 196         // ceil(50000/256) row tiles of 256
#define M_PAD 50176        // 196*256
#define SCAN_BLOCKS 49     // ceil(50000 / 1024)

typedef unsigned short ushort_t;
typedef short sh8 __attribute__((ext_vector_type(8)));
typedef float f32x4 __attribute__((ext_vector_type(4)));

__device__ __forceinline__ ushort_t f2bf(float f) {
    unsigned u = __float_as_uint(f);
    unsigned r = (u + 0x7FFFu + ((u >> 16) & 1u)) >> 16;
    return (ushort_t)r;
}
__device__ __forceinline__ float bf2f(ushort_t h) {
    return __uint_as_float(((unsigned)h) << 16);
}

// ---------------- zero fill ----------------
__global__ void zero_kernel(int* __restrict__ p, int n) {
    int i = blockIdx.x * 256 + threadIdx.x;
    if (i < n) p[i] = 0;
}

// ---------------- x -> bf16 into h0[:, :512] ----------------
__global__ void convert_x_kernel(const float* __restrict__ x, ushort_t* __restrict__ h0) {
    int t = blockIdx.x * 256 + threadIdx.x;      // 50000*128 threads
    int n = t >> 7, c = t & 127;
    float4 v = ((const float4*)x)[n * 128 + c];
    ushort4 o;
    o.x = f2bf(v.x); o.y = f2bf(v.y); o.z = f2bf(v.z); o.w = f2bf(v.w);
    ((ushort4*)h0)[n * 256 + c] = o;
}

// ---------------- W (K x N fp32) -> Wt (N x K bf16) ----------------
__global__ void wtrans_kernel(const float* __restrict__ W, ushort_t* __restrict__ Wt,
                              int K, int Nn) {
    __shared__ float t[32][33];
    int n0 = blockIdx.x * 32, k0 = blockIdx.y * 32;
    int tx = threadIdx.x, ty = threadIdx.y;  // 32 x 8
#pragma unroll
    for (int i = 0; i < 4; i++)
        t[ty + 8 * i][tx] = W[(size_t)(k0 + ty + 8 * i) * Nn + n0 + tx];
    __syncthreads();
#pragma unroll
    for (int i = 0; i < 4; i++)
        Wt[(size_t)(n0 + ty + 8 * i) * K + k0 + tx] = f2bf(t[tx][ty + 8 * i]);
}

// ---------------- CSR build ----------------
__global__ void hist_kernel(const int* __restrict__ edst, int* __restrict__ counts) {
    int e = blockIdx.x * 256 + threadIdx.x;
    atomicAdd(&counts[edst[e]], 1);
}

__global__ void scan_blocks_kernel(const int* __restrict__ counts, int* __restrict__ incl,
                                   int* __restrict__ block_sums) {
    __shared__ int s[1024];
    int b = blockIdx.x, tid = threadIdx.x;
    int i = b * 1024 + tid;
    int c = (i < NNODES) ? counts[i] : 0;
    s[tid] = c;
    __syncthreads();
    for (int off = 1; off < 1024; off <<= 1) {
        int v = (tid >= off) ? s[tid - off] : 0;
        __syncthreads();
        s[tid] += v;
        __syncthreads();
    }
    if (i < NNODES) incl[i] = s[tid];
    if (tid == 1023) block_sums[b] = s[1023];
}

__global__ void scan_sums_kernel(const int* __restrict__ block_sums, int* __restrict__ carry) {
    if (threadIdx.x == 0 && blockIdx.x == 0) {
        int run = 0;
        for (int b = 0; b < SCAN_BLOCKS; b++) { carry[b] = run; run += block_sums[b]; }
    }
}

__global__ void scan_finalize_kernel(const int* __restrict__ counts, const int* __restrict__ incl,
                                     const int* __restrict__ carry, int* __restrict__ offsets,
                                     int* __restrict__ cursor) {
    int b = blockIdx.x, tid = threadIdx.x;
    int i = b * 1024 + tid;
    if (i < NNODES) {
        int v = incl[i] + carry[b];
        offsets[i + 1] = v;
        cursor[i] = v - counts[i];
    }
    if (i == 0) offsets[0] = 0;
}

__global__ void scatter_kernel(const int* __restrict__ edst, int* __restrict__ cursor,
                               int* __restrict__ perm) {
    int e = blockIdx.x * 256 + threadIdx.x;
    int d = edst[e];
    int pos = atomicAdd(&cursor[d], 1);
    perm[pos] = e;
}

// ---------------- per-node aggregation: h0[:, 512:] = sum w_e * x_bf16[src] ----------------
__global__ void aggregate_kernel(ushort_t* __restrict__ h0,
                                 const float* __restrict__ ew,
                                 const int* __restrict__ esrc,
                                 const int* __restrict__ offsets,
                                 const int* __restrict__ perm) {
    __shared__ int se[128];
    __shared__ float swt[128];
    int n = blockIdx.x;
    int tid = threadIdx.x;  // 128 threads, 4 dims each
    int beg = offsets[n], end = offsets[n + 1];
    float a0 = 0.f, a1 = 0.f, a2 = 0.f, a3 = 0.f;
    for (int base = beg; base < end; base += 128) {
        int cnt = end - base; if (cnt > 128) cnt = 128;
        if (tid < cnt) {
            int e = perm[base + tid];
            se[tid] = esrc[e];
            swt[tid] = ew[e];
        }
        __syncthreads();
        for (int j = 0; j < cnt; j++) {
            int s = se[j];
            float w = swt[j];
            ushort4 v = *(const ushort4*)&h0[(size_t)s * 1024 + tid * 4];
            a0 += w * bf2f(v.x);
            a1 += w * bf2f(v.y);
            a2 += w * bf2f(v.z);
            a3 += w * bf2f(v.w);
        }
        __syncthreads();
    }
    ushort4 o;
    o.x = f2bf(a0); o.y = f2bf(a1); o.z = f2bf(a2); o.w = f2bf(a3);
    *(ushort4*)&h0[(size_t)n * 1024 + 512 + tid * 4] = o;
}

// =====================================================================================
// 256x256 8-phase bf16 MFMA GEMM (m201 structure): C(MxN) = A(MxK) * Bt(NxK)^T + bias
// 512 threads = 8 waves (2M x 4N); per-wave output 128x64; BK=64; LDS 128 KiB
// (2 dbuf x 2 half x 128x64 for each of A,B), st_16x32 XOR swizzle applied via
// pre-swizzled global source (linear global_load_lds dest) + swizzled ds_read.
// Counted vmcnt(4) once per K-tile (never 0 in steady state); setprio around MFMA.
// =====================================================================================
#define BAR() do { __builtin_amdgcn_sched_barrier(0); __builtin_amdgcn_s_barrier(); \
                   __builtin_amdgcn_sched_barrier(0); } while (0)

// stage one 16KB half-tile (2 x global_load_lds of 16B per thread)
#define STAGE(MAT, HALF, T, D) do {                                                      \
    _Pragma("unroll")                                                                    \
    for (int j = 0; j < 2; j++) {                                                        \
        const ushort_t* src = ((MAT) ? pb[j] : pa[j]) + (size_t)(HALF) * 128 * K + (size_t)(T) * 64; \
        __builtin_amdgcn_global_load_lds(                                                \
            (const __attribute__((address_space(1))) void*)src,                          \
            (__attribute__((address_space(3))) void*)(lds + ((MAT) * 32768u + (D) * 16384u + (HALF) * 8192u + (unsigned)(wid * 2 + j) * 512u)), \
            16, 0, 0);                                                                   \
    }                                                                                    \
} while (0)

// 8 A-frags (4 m x 2 ks) from this wave's A half-region
#define LDA(DST, MH, RB) do {                                                            \
    _Pragma("unroll")                                                                    \
    for (int mq = 0; mq < 4; mq++)                                                       \
        _Pragma("unroll")                                                                \
        for (int ks = 0; ks < 2; ks++)                                                   \
            DST[mq * 2 + ks] = *(const sh8*)(aL + (RB) + ((MH) * 4 + mq) * 2048 + ks * 1024); \
} while (0)

// 4 B-frags (2 n x 2 ks) from this wave's B half-region
#define LDB(DST, NH, RB) do {                                                            \
    _Pragma("unroll")                                                                    \
    for (int nq = 0; nq < 2; nq++)                                                       \
        _Pragma("unroll")                                                                \
        for (int ks = 0; ks < 2; ks++)                                                   \
            DST[nq * 2 + ks] = *(const sh8*)(bL + (RB) + ((NH) * 2 + nq) * 2048 + ks * 1024); \
} while (0)

// one C-quadrant: 16 MFMA (4 m x 2 n x 2 ks)
#define MM(AF, BF, MH, NH) do {                                                          \
    __builtin_amdgcn_s_setprio(1);                                                       \
    _Pragma("unroll")                                                                    \
    for (int mq = 0; mq < 4; mq++)                                                       \
        _Pragma("unroll")                                                                \
        for (int nq = 0; nq < 2; nq++)                                                   \
            _Pragma("unroll")                                                            \
            for (int ks = 0; ks < 2; ks++)                                               \
                acc[(MH) * 4 + mq][(NH) * 2 + nq] = __builtin_amdgcn_mfma_f32_16x16x32_bf16( \
                    AF[mq * 2 + ks], BF[nq * 2 + ks], acc[(MH) * 4 + mq][(NH) * 2 + nq], 0, 0, 0); \
    __builtin_amdgcn_s_setprio(0);                                                       \
} while (0)

// K-tile: 4 phases; stages A-halves of T+1 (phases A,B) and B-halves of T+2 (C,D)
#define TILE(T, D) do {                                                                  \
    LDA(af0, 0, (D) * 32768); LDB(bf0, 0, (D) * 32768);                                  \
    if ((T) + 1 < NT) STAGE(0, 0, (T) + 1, (D) ^ 1);                                     \
    BAR(); MM(af0, bf0, 0, 0); BAR();                                                    \
    LDB(bf1, 1, (D) * 32768);                                                            \
    if ((T) + 1 < NT) STAGE(0, 1, (T) + 1, (D) ^ 1);                                     \
    BAR(); MM(af0, bf1, 0, 1); BAR();                                                    \
    LDA(af1, 1, (D) * 32768);                                                            \
    if ((T) + 2 < NT) STAGE(1, 0, (T) + 2, (D));                                         \
    BAR(); MM(af1, bf1, 1, 1); BAR();                                                    \
    if ((T) + 2 < NT) {                                                                  \
        STAGE(1, 1, (T) + 2, (D));                                                       \
        asm volatile("s_waitcnt vmcnt(4)" ::: "memory");                                 \
    } else {                                                                             \
        asm volatile("s_waitcnt vmcnt(0)" ::: "memory");                                 \
    }                                                                                    \
    BAR(); MM(af1, bf0, 1, 0); BAR();                                                    \
} while (0)

template <int K, int NOUT, bool RELU, bool OUTBF16>
__launch_bounds__(512, 2)
__global__ void gemm256(const ushort_t* __restrict__ A, const ushort_t* __restrict__ B,
                        const float* __restrict__ bias, void* __restrict__ C, int Mvalid) {
    // [A: 2 dbuf x 2 half x 8192 u16][B: same] = 131072 bytes
    __shared__ __align__(16) ushort_t lds[65536];
    const int tid = threadIdx.x;
    const int wid = tid >> 6, lane = tid & 63;
    const int lrow = lane & 15, lq = lane >> 4;
    const int wm = wid >> 2, wn = wid & 3;
    const int m0 = blockIdx.y * 256, n0 = blockIdx.x * 256;
    const int NT = K / 64;

    // ---- staging source addresses (inverse-swizzled so linear LDS dest => swizzled content)
    // linear physical byte p within a 16KB half-tile; logical addr q = p ^ ((p>>9 & 1)<<5);
    // unswizzled subtiled layout: q = (row>>4)*2048 + (k>>5)*1024 + (row&15)*64 + (k&31)*2
    const ushort_t* pa[2];
    const ushort_t* pb[2];
#pragma unroll
    for (int j = 0; j < 2; j++) {
        int p = (wid * 2 + j) * 1024 + lane * 16;
        int q = p ^ (((p >> 9) & 1) << 5);
        int row = ((q >> 11) << 4) | ((q >> 6) & 15);
        int k   = (((q >> 10) & 1) << 5) | ((q & 63) >> 1);
        pa[j] = A + (size_t)(m0 + row) * K + k;
        pb[j] = B + (size_t)(n0 + row) * K + k;
    }

    // ---- ds_read base (swizzled): byte within region for (row_sub, ks) fragment reads
    const int abase = (lrow * 64 + lq * 16) ^ ((lrow & 8) << 2);
    const char* aL = (const char*)lds + wm * 16384 + abase;                                // A: dbuf via +D*32768
    const char* bL = (const char*)lds + 65536 + (wn >> 1) * 16384 + (wn & 1) * 8192 + abase;

    f32x4 acc[8][4] = {};
    sh8 af0[8], af1[8], bf0[4], bf1[4];

    // ---- prologue: T0 fully + T1 B-halves (12 loads/thread); wait T0 (keep 4 in flight)
    STAGE(0, 0, 0, 0); STAGE(0, 1, 0, 0); STAGE(1, 0, 0, 0); STAGE(1, 1, 0, 0);
    STAGE(1, 0, 1, 1); STAGE(1, 1, 1, 1);
    asm volatile("s_waitcnt vmcnt(4)" ::: "memory");
    BAR();

#pragma unroll 1
    for (int t = 0; t < NT; t += 2) {      // NT is even (K multiple of 128)
        TILE(t, 0);
        TILE(t + 1, 1);
    }

    // ---- epilogue: C/D frag layout col=lane&15, row=(lane>>4)*4+reg
    int gcol[4]; float bv[4];
#pragma unroll
    for (int nn = 0; nn < 4; nn++) {
        gcol[nn] = n0 + wn * 64 + nn * 16 + lrow;
        bv[nn] = bias[gcol[nn]];
    }
#pragma unroll
    for (int mm = 0; mm < 8; mm++) {
#pragma unroll
        for (int r = 0; r < 4; r++) {
            int gm = m0 + wm * 128 + mm * 16 + lq * 4 + r;
#pragma unroll
            for (int nn = 0; nn < 4; nn++) {
                float v = acc[mm][nn][r] + bv[nn];
                if (RELU) v = v > 0.f ? v : 0.f;
                if (OUTBF16) {
                    ((ushort_t*)C)[(size_t)gm * NOUT + gcol[nn]] = f2bf(v);
                } else {
                    if (gm < Mvalid) ((float*)C)[(size_t)gm * NOUT + gcol[nn]] = v;
                }
            }
        }
    }
}

static inline size_t align256(size_t x) { return (x + 255) & ~(size_t)255; }

extern "C" void kernel_launch(void* const* d_in, const int* in_sizes, int n_in,
                              void* d_out, int out_size, void* d_ws, size_t ws_size,
                              hipStream_t stream) {
    const float* x   = (const float*)d_in[0];
    const float* ew  = (const float*)d_in[1];
    const float* W1  = (const float*)d_in[2];
    const float* b1  = (const float*)d_in[3];
    const float* W2  = (const float*)d_in[4];
    const float* b2  = (const float*)d_in[5];
    const float* W3  = (const float*)d_in[6];
    const float* b3  = (const float*)d_in[7];
    const int* esrc  = (const int*)d_in[8];
    const int* edst  = (const int*)d_in[9];
    float* out = (float*)d_out;

    // Fixed workspace: h0 (102.8 MB, M_PAD x 1024 bf16) + bf16 weights (14.5 MB).
    // Chunk area (rest of ws): h1c + h2c, dynamically sized from ws_size.
    // CSR arrays (7 MB) aliased at the start of the chunk area (dead before GEMM1).
    char* ws = (char*)d_ws;
    size_t off = 0;
    ushort_t* h0  = (ushort_t*)(ws + off); off = align256(off + (size_t)M_PAD * 1024 * 2);
    ushort_t* w1t = (ushort_t*)(ws + off); off = align256(off + (size_t)H1 * K1 * 2);
    ushort_t* w2t = (ushort_t*)(ws + off); off = align256(off + (size_t)H2 * H1 * 2);
    ushort_t* w3t = (ushort_t*)(ws + off); off = align256(off + (size_t)OUT_DIM * H2 * 2);
    size_t fixed_end = off;

    // Dynamic chunk tiles: each 256-row tile needs 256*2048*2 bytes in each of h1c/h2c.
    const size_t per_tile = (size_t)256 * 2048 * 2 * 2;  // 2 MiB
    size_t avail = (ws_size > fixed_end + 512) ? (ws_size - fixed_end - 512) : 0;
    int T = (int)(avail / per_tile);
    if (T > MTILES) T = MTILES;
    if (T < 4) T = 4;  // 4 tiles = 8 MiB chunk area >= CSR alias (7.1 MB)
    int nchunks = (MTILES + T - 1) / T;
    T = (MTILES + nchunks - 1) / nchunks;  // balance chunk sizes

    ushort_t* h1c = (ushort_t*)(ws + fixed_end);
    ushort_t* h2c = (ushort_t*)(ws + fixed_end + (size_t)T * 256 * 2048 * 2);

    // CSR arrays aliased into chunk area (used only before the first GEMM)
    size_t coff = fixed_end;
    int* counts     = (int*)(ws + coff); coff = align256(coff + (size_t)NNODES * 4);
    int* offsets    = (int*)(ws + coff); coff = align256(coff + (size_t)(NNODES + 1) * 4);
    int* cursor     = (int*)(ws + coff); coff = align256(coff + (size_t)NNODES * 4);
    int* incl       = (int*)(ws + coff); coff = align256(coff + (size_t)NNODES * 4);
    int* perm       = (int*)(ws + coff); coff = align256(coff + (size_t)NEDGES * 4);
    int* block_sums = (int*)(ws + coff); coff = align256(coff + (size_t)SCAN_BLOCKS * 4);
    int* carry      = (int*)(ws + coff); coff = align256(coff + (size_t)SCAN_BLOCKS * 4);

    // counts = 0
    zero_kernel<<<(NNODES + 255) / 256, 256, 0, stream>>>(counts, NNODES);

    // x -> bf16 h0[:, :512]
    convert_x_kernel<<<25000, 256, 0, stream>>>(x, h0);

    // zero h0 pad rows [50000, 50176) (full 1024 cols): 176*1024*2/4 ints
    zero_kernel<<<(90112 + 255) / 256, 256, 0, stream>>>((int*)(h0 + (size_t)NNODES * 1024), 90112);

    // weight transposes (fp32 KxN -> bf16 NxK)
    wtrans_kernel<<<dim3(H1 / 32, K1 / 32), dim3(32, 8), 0, stream>>>(W1, w1t, K1, H1);
    wtrans_kernel<<<dim3(H2 / 32, H1 / 32), dim3(32, 8), 0, stream>>>(W2, w2t, H1, H2);
    wtrans_kernel<<<dim3(OUT_DIM / 32, H2 / 32), dim3(32, 8), 0, stream>>>(W3, w3t, H2, OUT_DIM);

    // CSR by dst (hierarchical scan)
    hist_kernel<<<NEDGES / 256, 256, 0, stream>>>(edst, counts);
    scan_blocks_kernel<<<SCAN_BLOCKS, 1024, 0, stream>>>(counts, incl, block_sums);
    scan_sums_kernel<<<1, 64, 0, stream>>>(block_sums, carry);
    scan_finalize_kernel<<<SCAN_BLOCKS, 1024, 0, stream>>>(counts, incl, carry, offsets, cursor);
    scatter_kernel<<<NEDGES / 256, 256, 0, stream>>>(edst, cursor, perm);

    // aggregate into h0[:, 512:]
    aggregate_kernel<<<NNODES, 128, 0, stream>>>(h0, ew, esrc, offsets, perm);

    // MLP in M-chunks of T 256-row tiles
    for (int t0 = 0; t0 < MTILES; t0 += T) {
        int tiles = MTILES - t0; if (tiles > T) tiles = T;
        int row0 = t0 * 256;
        gemm256<K1, H1, true, true><<<dim3(H1 / 256, tiles), 512, 0, stream>>>(
            h0 + (size_t)row0 * K1, w1t, b1, h1c, 0);
        gemm256<H1, H2, true, true><<<dim3(H2 / 256, tiles), 512, 0, stream>>>(
            h1c, w2t, b2, h2c, 0);
        gemm256<H2, OUT_DIM, false, false><<<dim3(OUT_DIM / 256, tiles), 512, 0, stream>>>(
            h2c, w3t, b3, out + (size_t)row0 * OUT_DIM, NNODES - row0);
    }
}